// Round 1
// 516.466 us; speedup vs baseline: 1.0000x; 1.0000x over previous
//
#include <hip/hip_runtime.h>
#include <math.h>

// RNNT joint + log_softmax over vocab.
//   f: [B,T,V] fp32, g: [B,U,V] fp32
//   out[b,t,u,v] = x - (max_v x + log(sum_v exp(x - max_v x))),  x = f[b,t,v] + g[b,u,v]
// B=4, T=256, U=128, V=1024.
//
// One wave (64 lanes) per PAIR of (b,t,u) rows sharing the same f row:
//   - f row (1024 floats = 16 VGPR/lane) loaded once, reused for u0 and u0+1
//   - two fully independent reduction chains interleaved 2-wide so the
//     12 shuffle stages + exp pass of row0 overlap with row1's
//   - exp(x-m) computed as v_exp_f32(fma(x, log2e, -m*log2e)): 1 FMA + 1 trans
// Entire rows live in registers; wave shuffle butterflies only, no LDS.

#define RB 4
#define RT 256
#define RU 128
#define RV 1024

typedef float nfloat4 __attribute__((ext_vector_type(4)));  // native vec for nontemporal store

__global__ __launch_bounds__(256, 6) void rnnt_joint_ls_kernel(
    const float* __restrict__ f,
    const float* __restrict__ g,
    float* __restrict__ out)
{
    const int wave = threadIdx.x >> 6;
    const int lane = threadIdx.x & 63;
    const int p = blockIdx.x * 4 + wave;     // pair index in [0, B*T*U/2)

    // pair p -> (b, t, u0) with u0 = 2*(p % (U/2)), bt = p / (U/2)
    const int pu = p & 63;                   // U/2 = 64
    const int bt = p >> 6;                   // b*T + t
    const int b  = bt >> 8;                  // T = 256
    const int u0 = pu * 2;

    const float4* __restrict__ f4 = (const float4*)(f + (size_t)bt * RV);
    const float4* __restrict__ g4 = (const float4*)(g + ((size_t)b * RU + u0) * RV);
    nfloat4* __restrict__ o4 = (nfloat4*)(out + ((size_t)bt * RU + u0) * RV);

    // ---- load f once, build both rows ----
    float4 fv[4];
#pragma unroll
    for (int i = 0; i < 4; ++i) fv[i] = f4[lane + 64 * i];

    float4 x0[4], x1[4];
#pragma unroll
    for (int i = 0; i < 4; ++i) {
        float4 gv = g4[lane + 64 * i];             // row u0
        x0[i].x = fv[i].x + gv.x;
        x0[i].y = fv[i].y + gv.y;
        x0[i].z = fv[i].z + gv.z;
        x0[i].w = fv[i].w + gv.w;
    }
#pragma unroll
    for (int i = 0; i < 4; ++i) {
        float4 gv = g4[256 + lane + 64 * i];       // row u0+1 (next 4 KB)
        x1[i].x = fv[i].x + gv.x;
        x1[i].y = fv[i].y + gv.y;
        x1[i].z = fv[i].z + gv.z;
        x1[i].w = fv[i].w + gv.w;
    }

    // ---- dual wave max reductions (interleaved) ----
    float m0 = -INFINITY, m1 = -INFINITY;
#pragma unroll
    for (int i = 0; i < 4; ++i) {
        m0 = fmaxf(m0, fmaxf(fmaxf(x0[i].x, x0[i].y), fmaxf(x0[i].z, x0[i].w)));
        m1 = fmaxf(m1, fmaxf(fmaxf(x1[i].x, x1[i].y), fmaxf(x1[i].z, x1[i].w)));
    }
#pragma unroll
    for (int off = 32; off > 0; off >>= 1) {
        m0 = fmaxf(m0, __shfl_xor(m0, off, 64));
        m1 = fmaxf(m1, __shfl_xor(m1, off, 64));
    }

    // ---- dual sum(exp(x - m)) reductions (interleaved) ----
    // exp(x - m) = exp2(x*log2e - m*log2e): one v_fma + one v_exp per element
    const float kL2E = 1.4426950408889634f;
    const float c0 = m0 * kL2E;
    const float c1 = m1 * kL2E;
    float s0 = 0.0f, s1 = 0.0f;
#pragma unroll
    for (int i = 0; i < 4; ++i) {
        s0 += exp2f(fmaf(x0[i].x, kL2E, -c0));
        s1 += exp2f(fmaf(x1[i].x, kL2E, -c1));
        s0 += exp2f(fmaf(x0[i].y, kL2E, -c0));
        s1 += exp2f(fmaf(x1[i].y, kL2E, -c1));
        s0 += exp2f(fmaf(x0[i].z, kL2E, -c0));
        s1 += exp2f(fmaf(x1[i].z, kL2E, -c1));
        s0 += exp2f(fmaf(x0[i].w, kL2E, -c0));
        s1 += exp2f(fmaf(x1[i].w, kL2E, -c1));
    }
#pragma unroll
    for (int off = 32; off > 0; off >>= 1) {
        s0 += __shfl_xor(s0, off, 64);
        s1 += __shfl_xor(s1, off, 64);
    }

    const float M0 = m0 + __logf(s0);
    const float M1 = m1 + __logf(s1);

    // ---- streaming writes (non-temporal: output is never re-read) ----
#pragma unroll
    for (int i = 0; i < 4; ++i) {
        nfloat4 y;
        y.x = x0[i].x - M0;
        y.y = x0[i].y - M0;
        y.z = x0[i].z - M0;
        y.w = x0[i].w - M0;
        __builtin_nontemporal_store(y, &o4[lane + 64 * i]);
    }
#pragma unroll
    for (int i = 0; i < 4; ++i) {
        nfloat4 y;
        y.x = x1[i].x - M1;
        y.y = x1[i].y - M1;
        y.z = x1[i].z - M1;
        y.w = x1[i].w - M1;
        __builtin_nontemporal_store(y, &o4[256 + lane + 64 * i]);
    }
}

extern "C" void kernel_launch(void* const* d_in, const int* in_sizes, int n_in,
                              void* d_out, int out_size, void* d_ws, size_t ws_size,
                              hipStream_t stream) {
    const float* f = (const float*)d_in[0];   // [B,T,V]
    const float* g = (const float*)d_in[1];   // [B,U,V]
    float* out = (float*)d_out;               // [B,T,U,V]

    const int pairs = RB * RT * RU / 2;       // 65536 row-pairs
    dim3 grid(pairs / 4);                     // 4 waves per block, 2 rows per wave
    dim3 block(256);
    rnnt_joint_ls_kernel<<<grid, block, 0, stream>>>(f, g, out);
}